// Round 1
// baseline (204.436 us; speedup 1.0000x reference)
//
#include <hip/hip_runtime.h>
#include <math.h>

// BlockNet: 4× (unfold-linear ⊕ conv ⊕ sigmoid-gate blend, ReLU) + FC(32->4).
// Input x: (B,3,64,64) f32.  Output: (B,4) f32.
// CFG: (cin,cout,k,s,oh) = (3,4,5,3,20),(4,6,3,2,9),(6,16,3,2,4),(16,32,3,2,1)

__device__ __forceinline__ float sigmoidf_(float x) {
    return 1.0f / (1.0f + expf(-x));
}

// Generic block kernel: one workgroup stages BPB batches' input tiles in LDS,
// then each thread computes one (batch, output-location) task.
template<int CIN, int COUT, int K, int S, int OH, int IH, int BPB>
__global__ __launch_bounds__(256)
void block_kernel(const float* __restrict__ in,    // (B, CIN, IH, IH)
                  const float* __restrict__ w_uc,  // (L*LN, COUT)
                  const float* __restrict__ b_uc,  // (COUT, OH, OH)
                  const float* __restrict__ w_pc,  // (COUT, CIN, K, K)
                  const float* __restrict__ b_pc,  // (COUT)
                  const float* __restrict__ w_wl,  // (CIN*K*K)
                  const float* __restrict__ b_wl,  // (1)
                  float* __restrict__ out,         // (B, COUT, OH, OH)
                  int B)
{
    constexpr int LN   = CIN * K * K;
    constexpr int L    = OH * OH;
    constexpr int TILE = CIN * IH * IH;
    __shared__ __align__(16) float lds[BPB * TILE];

    const int b0 = blockIdx.x * BPB;
    const int nb = (B - b0 < BPB) ? (B - b0) : BPB;
    const int tot = nb * TILE;
    const float* src = in + (size_t)b0 * TILE;
    if ((tot & 3) == 0) {
        const float4* s4 = reinterpret_cast<const float4*>(src);
        float4* d4 = reinterpret_cast<float4*>(lds);
        for (int idx = threadIdx.x; idx < (tot >> 2); idx += blockDim.x) d4[idx] = s4[idx];
    } else {
        for (int idx = threadIdx.x; idx < tot; idx += blockDim.x) lds[idx] = src[idx];
    }
    __syncthreads();

    const float bwl = b_wl[0];
    for (int t = threadIdx.x; t < nb * L; t += blockDim.x) {
        const int bb = t / L;
        const int l  = t % L;
        const int i  = l / OH, j = l % OH;
        const float* tile = lds + bb * TILE;

        float acc_uc[COUT], acc_pc[COUT];
        #pragma unroll
        for (int o = 0; o < COUT; ++o) { acc_uc[o] = 0.f; acc_pc[o] = 0.f; }
        float acc_g = 0.f;

        const float* wu = w_uc + (size_t)l * LN * COUT;
        #pragma unroll
        for (int c = 0; c < CIN; ++c)
        #pragma unroll
        for (int a = 0; a < K; ++a)
        #pragma unroll
        for (int b2 = 0; b2 < K; ++b2) {
            const int n = c * K * K + a * K + b2;
            const float v = tile[c * IH * IH + (i * S + a) * IH + (j * S + b2)];
            acc_g += v * w_wl[n];
            if constexpr ((COUT & 3) == 0) {
                const float4* wu4 = reinterpret_cast<const float4*>(wu + n * COUT);
                #pragma unroll
                for (int o4 = 0; o4 < COUT / 4; ++o4) {
                    const float4 w4 = wu4[o4];
                    acc_uc[o4 * 4 + 0] += v * w4.x;
                    acc_uc[o4 * 4 + 1] += v * w4.y;
                    acc_uc[o4 * 4 + 2] += v * w4.z;
                    acc_uc[o4 * 4 + 3] += v * w4.w;
                }
            } else {
                #pragma unroll
                for (int o = 0; o < COUT; ++o) acc_uc[o] += v * wu[n * COUT + o];
            }
            #pragma unroll
            for (int o = 0; o < COUT; ++o) acc_pc[o] += v * w_pc[o * LN + n];
        }

        const float g = sigmoidf_(acc_g + bwl);
        const size_t ob = (size_t)(b0 + bb) * COUT * L;
        #pragma unroll
        for (int o = 0; o < COUT; ++o) {
            const float x1 = acc_uc[o] + b_uc[o * L + l];
            const float x2 = acc_pc[o] + b_pc[o];
            const float y  = x1 * g + x2 * (1.f - g);
            out[ob + o * L + l] = fmaxf(y, 0.f);
        }
    }
}

// Block 4 (cin=16, cout=32, k=3, s=2, ih=4, oh=1) fused with FC(32->4).
// 32 lanes per batch (one per cout), 8 batches per 256-thread workgroup.
__global__ __launch_bounds__(256)
void block4_fc_kernel(const float* __restrict__ in,    // (B,16,4,4)
                      const float* __restrict__ w_uc,  // (144,32)
                      const float* __restrict__ b_uc,  // (32)
                      const float* __restrict__ w_pc,  // (32,144)
                      const float* __restrict__ b_pc,  // (32)
                      const float* __restrict__ w_wl,  // (144)
                      const float* __restrict__ b_wl,  // (1)
                      const float* __restrict__ fc_w,  // (32,4)
                      const float* __restrict__ fc_b,  // (4)
                      float* __restrict__ out,         // (B,4)
                      int B)
{
    __shared__ float hbuf[8][32];
    const int bl = threadIdx.x >> 5;
    const int o  = threadIdx.x & 31;
    const int b  = blockIdx.x * 8 + bl;

    if (b < B) {
        const float* xb = in + (size_t)b * 256;
        float acc_uc = 0.f, acc_pc = 0.f, acc_g = 0.f;
        #pragma unroll
        for (int c = 0; c < 16; ++c)
        #pragma unroll
        for (int a = 0; a < 3; ++a)
        #pragma unroll
        for (int b2 = 0; b2 < 3; ++b2) {
            const int n = c * 9 + a * 3 + b2;
            const float v = xb[c * 16 + a * 4 + b2];
            acc_uc += v * w_uc[n * 32 + o];
            acc_pc += v * w_pc[o * 144 + n];
            acc_g  += v * w_wl[n];
        }
        const float g  = sigmoidf_(acc_g + b_wl[0]);
        const float x1 = acc_uc + b_uc[o];
        const float x2 = acc_pc + b_pc[o];
        hbuf[bl][o] = fmaxf(x1 * g + x2 * (1.f - g), 0.f);
    }
    __syncthreads();

    if (threadIdx.x < 32) {
        const int bl2 = threadIdx.x >> 2;
        const int f   = threadIdx.x & 3;
        const int bb  = blockIdx.x * 8 + bl2;
        if (bb < B) {
            float s = fc_b[f];
            #pragma unroll
            for (int oo = 0; oo < 32; ++oo) s += hbuf[bl2][oo] * fc_w[oo * 4 + f];
            out[(size_t)bb * 4 + f] = s;
        }
    }
}

extern "C" void kernel_launch(void* const* d_in, const int* in_sizes, int n_in,
                              void* d_out, int out_size, void* d_ws, size_t ws_size,
                              hipStream_t stream) {
    const float* x    = (const float*)d_in[0];
    const float* wuc1 = (const float*)d_in[1];
    const float* buc1 = (const float*)d_in[2];
    const float* wpc1 = (const float*)d_in[3];
    const float* bpc1 = (const float*)d_in[4];
    const float* wwl1 = (const float*)d_in[5];
    const float* bwl1 = (const float*)d_in[6];
    const float* wuc2 = (const float*)d_in[7];
    const float* buc2 = (const float*)d_in[8];
    const float* wpc2 = (const float*)d_in[9];
    const float* bpc2 = (const float*)d_in[10];
    const float* wwl2 = (const float*)d_in[11];
    const float* bwl2 = (const float*)d_in[12];
    const float* wuc3 = (const float*)d_in[13];
    const float* buc3 = (const float*)d_in[14];
    const float* wpc3 = (const float*)d_in[15];
    const float* bpc3 = (const float*)d_in[16];
    const float* wwl3 = (const float*)d_in[17];
    const float* bwl3 = (const float*)d_in[18];
    const float* wuc4 = (const float*)d_in[19];
    const float* buc4 = (const float*)d_in[20];
    const float* wpc4 = (const float*)d_in[21];
    const float* bpc4 = (const float*)d_in[22];
    const float* wwl4 = (const float*)d_in[23];
    const float* bwl4 = (const float*)d_in[24];
    const float* fcw  = (const float*)d_in[25];
    const float* fcb  = (const float*)d_in[26];

    const int B = in_sizes[0] / (3 * 64 * 64);   // 2048

    float* ws = (float*)d_ws;
    float* y1 = ws;                               // (B,4,20,20)  = B*1600
    float* y2 = y1 + (size_t)B * 4 * 400;         // (B,6,9,9)    = B*486
    float* y3 = y2 + (size_t)B * 6 * 81;          // (B,16,4,4)   = B*256

    dim3 blk(256);

    // Block 1: cin=3,cout=4,k=5,s=3,oh=20,ih=64 ; 1 batch / WG (48 KB LDS)
    block_kernel<3, 4, 5, 3, 20, 64, 1>
        <<<B, blk, 0, stream>>>(x, wuc1, buc1, wpc1, bpc1, wwl1, bwl1, y1, B);

    // Block 2: cin=4,cout=6,k=3,s=2,oh=9,ih=20 ; 4 batches / WG
    block_kernel<4, 6, 3, 2, 9, 20, 4>
        <<<(B + 3) / 4, blk, 0, stream>>>(y1, wuc2, buc2, wpc2, bpc2, wwl2, bwl2, y2, B);

    // Block 3: cin=6,cout=16,k=3,s=2,oh=4,ih=9 ; 16 batches / WG
    block_kernel<6, 16, 3, 2, 4, 9, 16>
        <<<(B + 15) / 16, blk, 0, stream>>>(y2, wuc3, buc3, wpc3, bpc3, wwl3, bwl3, y3, B);

    // Block 4 + FC fused
    block4_fc_kernel<<<(B + 7) / 8, blk, 0, stream>>>(
        y3, wuc4, buc4, wpc4, bpc4, wwl4, bwl4, fcw, fcb, (float*)d_out, B);
}

// Round 2
// 164.962 us; speedup vs baseline: 1.2393x; 1.2393x over previous
//
#include <hip/hip_runtime.h>
#include <math.h>

// BlockNet: 4× (unfold-linear ⊕ conv ⊕ sigmoid-gate blend, ReLU) + FC(32->4).
// Strategy: transpose x to batch-last (P,B), then every block kernel uses
// lane=batch: weights wave-uniform (scalar loads), activations coalesced.
// CFG: (cin,cout,k,s,oh) = (3,4,5,3,20),(4,6,3,2,9),(6,16,3,2,4),(16,32,3,2,1)

__device__ __forceinline__ float sigmoidf_(float x) {
    return 1.0f / (1.0f + expf(-x));
}

// ---------------- transpose: in (R,C) -> out (C,R), R=B, C=12288 ----------
__global__ __launch_bounds__(256)
void transpose_kernel(const float* __restrict__ in, float* __restrict__ out,
                      int R, int C)
{
    __shared__ float tile[64][65];
    const int c0 = blockIdx.x * 64;   // column block (pixel dim)
    const int r0 = blockIdx.y * 64;   // row block (batch dim)
    const int x  = threadIdx.x & 63;
    const int y0 = threadIdx.x >> 6;  // 0..3
    #pragma unroll
    for (int r = 0; r < 16; ++r) {
        const int row = y0 * 16 + r;                        // batch-local
        tile[x][row] = in[(size_t)(r0 + row) * C + c0 + x]; // coalesced read
    }
    __syncthreads();
    #pragma unroll
    for (int r = 0; r < 16; ++r) {
        const int prow = y0 * 16 + r;                       // pixel-local
        out[(size_t)(c0 + prow) * R + r0 + x] = tile[prow][x]; // coalesced write
    }
}

// ------------- batch-last block kernel: wave owns one location l ----------
// in_t (CIN*IH*IH, B) ; out_t (COUT*L, B).  VB batches per thread.
template<int CIN, int COUT, int K, int S, int OH, int IH, int VB>
__global__ __launch_bounds__(256)
void blockT_kernel(const float* __restrict__ in_t,
                   const float* __restrict__ w_uc,  // (L*LN, COUT)
                   const float* __restrict__ b_uc,  // (COUT*L)
                   const float* __restrict__ w_pc,  // (COUT, LN)
                   const float* __restrict__ b_pc,  // (COUT)
                   const float* __restrict__ w_wl,  // (LN)
                   const float* __restrict__ b_wl,  // (1)
                   float* __restrict__ out_t,
                   int B)
{
    constexpr int LN = CIN * K * K;
    constexpr int L  = OH * OH;
    const int wv   = threadIdx.x >> 6;
    const int lane = threadIdx.x & 63;
    const int l    = __builtin_amdgcn_readfirstlane(blockIdx.y * 4 + wv);
    if (l >= L) return;                       // wave-uniform, no syncthreads
    const int i = l / OH, j = l % OH;
    const int b = blockIdx.x * (64 * VB) + lane * VB;

    float au[COUT][VB], ap[COUT][VB], ag[VB];
    #pragma unroll
    for (int o = 0; o < COUT; ++o)
        #pragma unroll
        for (int q = 0; q < VB; ++q) { au[o][q] = 0.f; ap[o][q] = 0.f; }
    #pragma unroll
    for (int q = 0; q < VB; ++q) ag[q] = 0.f;

    const float* wu = w_uc + (size_t)l * LN * COUT;

    #pragma unroll
    for (int c = 0; c < CIN; ++c)
    #pragma unroll
    for (int a = 0; a < K; ++a)
    #pragma unroll
    for (int b2 = 0; b2 < K; ++b2) {
        const int n = c * K * K + a * K + b2;
        const int p = c * IH * IH + (i * S + a) * IH + (j * S + b2);
        float v[VB];
        const float* src = in_t + (size_t)p * B + b;
        if constexpr (VB == 4) {
            const float4 t = *reinterpret_cast<const float4*>(src);
            v[0] = t.x; v[1] = t.y; v[2] = t.z; v[3] = t.w;
        } else if constexpr (VB == 2) {
            const float2 t = *reinterpret_cast<const float2*>(src);
            v[0] = t.x; v[1] = t.y;
        } else {
            v[0] = src[0];
        }
        const float wl = w_wl[n];
        #pragma unroll
        for (int q = 0; q < VB; ++q) ag[q] += v[q] * wl;
        #pragma unroll
        for (int o = 0; o < COUT; ++o) {
            const float wuv = wu[n * COUT + o];     // scalar (l uniform)
            const float wpv = w_pc[o * LN + n];     // scalar
            #pragma unroll
            for (int q = 0; q < VB; ++q) {
                au[o][q] += v[q] * wuv;
                ap[o][q] += v[q] * wpv;
            }
        }
    }

    const float bwl = b_wl[0];
    float g[VB];
    #pragma unroll
    for (int q = 0; q < VB; ++q) g[q] = sigmoidf_(ag[q] + bwl);

    #pragma unroll
    for (int o = 0; o < COUT; ++o) {
        const float buc = b_uc[o * L + l];
        const float bpc = b_pc[o];
        float y[VB];
        #pragma unroll
        for (int q = 0; q < VB; ++q) {
            const float x1 = au[o][q] + buc;
            const float x2 = ap[o][q] + bpc;
            y[q] = fmaxf(x1 * g[q] + x2 * (1.f - g[q]), 0.f);
        }
        float* dst = out_t + (size_t)(o * L + l) * B + b;
        if constexpr (VB == 4) {
            float4 t; t.x = y[0]; t.y = y[1]; t.z = y[2]; t.w = y[3];
            *reinterpret_cast<float4*>(dst) = t;
        } else if constexpr (VB == 2) {
            float2 t; t.x = y[0]; t.y = y[1];
            *reinterpret_cast<float2*>(dst) = t;
        } else {
            dst[0] = y[0];
        }
    }
}

// ---------- block4 (cin=16,k=3,s=2,oh=1,cout=32) + FC(32->4), batch-last ---
// grid = B/64, 256 threads: wave w handles cout octet [8w,8w+8), lane=batch.
__global__ __launch_bounds__(256)
void block4T_fc(const float* __restrict__ in_t,  // (256, B)
                const float* __restrict__ w_uc,  // (144,32)
                const float* __restrict__ b_uc,  // (32)
                const float* __restrict__ w_pc,  // (32,144)
                const float* __restrict__ b_pc,  // (32)
                const float* __restrict__ w_wl,  // (144)
                const float* __restrict__ b_wl,  // (1)
                const float* __restrict__ fc_w,  // (32,4)
                const float* __restrict__ fc_b,  // (4)
                float* __restrict__ out,         // (B,4)
                int B)
{
    __shared__ float red[4][64][5];
    const int wv   = threadIdx.x >> 6;
    const int lane = threadIdx.x & 63;
    const int o0   = __builtin_amdgcn_readfirstlane(wv * 8);
    const int b    = blockIdx.x * 64 + lane;

    float au[8], apc[8], ag = 0.f;
    #pragma unroll
    for (int oo = 0; oo < 8; ++oo) { au[oo] = 0.f; apc[oo] = 0.f; }

    #pragma unroll
    for (int c = 0; c < 16; ++c)
    #pragma unroll
    for (int a = 0; a < 3; ++a)
    #pragma unroll
    for (int b2 = 0; b2 < 3; ++b2) {
        const int n = c * 9 + a * 3 + b2;
        const int p = c * 16 + a * 4 + b2;
        const float v = in_t[(size_t)p * B + b];
        ag += v * w_wl[n];
        #pragma unroll
        for (int oo = 0; oo < 8; ++oo) {
            au[oo]  += v * w_uc[n * 32 + o0 + oo];
            apc[oo] += v * w_pc[(o0 + oo) * 144 + n];
        }
    }
    const float g = sigmoidf_(ag + b_wl[0]);
    float pf[4] = {0.f, 0.f, 0.f, 0.f};
    #pragma unroll
    for (int oo = 0; oo < 8; ++oo) {
        const int o = o0 + oo;
        const float h = fmaxf((au[oo] + b_uc[o]) * g +
                              (apc[oo] + b_pc[o]) * (1.f - g), 0.f);
        #pragma unroll
        for (int f = 0; f < 4; ++f) pf[f] += h * fc_w[o * 4 + f];
    }
    #pragma unroll
    for (int f = 0; f < 4; ++f) red[wv][lane][f] = pf[f];
    __syncthreads();
    if (wv == 0) {
        float4 s;
        s.x = fc_b[0] + red[0][lane][0] + red[1][lane][0] + red[2][lane][0] + red[3][lane][0];
        s.y = fc_b[1] + red[0][lane][1] + red[1][lane][1] + red[2][lane][1] + red[3][lane][1];
        s.z = fc_b[2] + red[0][lane][2] + red[1][lane][2] + red[2][lane][2] + red[3][lane][2];
        s.w = fc_b[3] + red[0][lane][3] + red[1][lane][3] + red[2][lane][3] + red[3][lane][3];
        *reinterpret_cast<float4*>(out + (size_t)b * 4) = s;
    }
}

// ======================= fallback path (round-1, NCHW) ====================
template<int CIN, int COUT, int K, int S, int OH, int IH, int BPB>
__global__ __launch_bounds__(256)
void block_kernel(const float* __restrict__ in,
                  const float* __restrict__ w_uc,
                  const float* __restrict__ b_uc,
                  const float* __restrict__ w_pc,
                  const float* __restrict__ b_pc,
                  const float* __restrict__ w_wl,
                  const float* __restrict__ b_wl,
                  float* __restrict__ out,
                  int B)
{
    constexpr int LN   = CIN * K * K;
    constexpr int L    = OH * OH;
    constexpr int TILE = CIN * IH * IH;
    __shared__ __align__(16) float lds[BPB * TILE];

    const int b0 = blockIdx.x * BPB;
    const int nb = (B - b0 < BPB) ? (B - b0) : BPB;
    const int tot = nb * TILE;
    const float* src = in + (size_t)b0 * TILE;
    if ((tot & 3) == 0) {
        const float4* s4 = reinterpret_cast<const float4*>(src);
        float4* d4 = reinterpret_cast<float4*>(lds);
        for (int idx = threadIdx.x; idx < (tot >> 2); idx += blockDim.x) d4[idx] = s4[idx];
    } else {
        for (int idx = threadIdx.x; idx < tot; idx += blockDim.x) lds[idx] = src[idx];
    }
    __syncthreads();

    const float bwl = b_wl[0];
    for (int t = threadIdx.x; t < nb * L; t += blockDim.x) {
        const int bb = t / L;
        const int l  = t % L;
        const int i  = l / OH, j = l % OH;
        const float* tile = lds + bb * TILE;

        float acc_uc[COUT], acc_pc[COUT];
        #pragma unroll
        for (int o = 0; o < COUT; ++o) { acc_uc[o] = 0.f; acc_pc[o] = 0.f; }
        float acc_g = 0.f;

        const float* wu = w_uc + (size_t)l * LN * COUT;
        #pragma unroll
        for (int c = 0; c < CIN; ++c)
        #pragma unroll
        for (int a = 0; a < K; ++a)
        #pragma unroll
        for (int b2 = 0; b2 < K; ++b2) {
            const int n = c * K * K + a * K + b2;
            const float v = tile[c * IH * IH + (i * S + a) * IH + (j * S + b2)];
            acc_g += v * w_wl[n];
            #pragma unroll
            for (int o = 0; o < COUT; ++o) acc_uc[o] += v * wu[n * COUT + o];
            #pragma unroll
            for (int o = 0; o < COUT; ++o) acc_pc[o] += v * w_pc[o * LN + n];
        }

        const float g = sigmoidf_(acc_g + bwl);
        const size_t ob = (size_t)(b0 + bb) * COUT * L;
        #pragma unroll
        for (int o = 0; o < COUT; ++o) {
            const float x1 = acc_uc[o] + b_uc[o * L + l];
            const float x2 = acc_pc[o] + b_pc[o];
            out[ob + o * L + l] = fmaxf(x1 * g + x2 * (1.f - g), 0.f);
        }
    }
}

__global__ __launch_bounds__(256)
void block4_fc_kernel(const float* __restrict__ in,
                      const float* __restrict__ w_uc,
                      const float* __restrict__ b_uc,
                      const float* __restrict__ w_pc,
                      const float* __restrict__ b_pc,
                      const float* __restrict__ w_wl,
                      const float* __restrict__ b_wl,
                      const float* __restrict__ fc_w,
                      const float* __restrict__ fc_b,
                      float* __restrict__ out,
                      int B)
{
    __shared__ float hbuf[8][32];
    const int bl = threadIdx.x >> 5;
    const int o  = threadIdx.x & 31;
    const int b  = blockIdx.x * 8 + bl;

    if (b < B) {
        const float* xb = in + (size_t)b * 256;
        float acc_uc = 0.f, acc_pc = 0.f, acc_g = 0.f;
        #pragma unroll
        for (int c = 0; c < 16; ++c)
        #pragma unroll
        for (int a = 0; a < 3; ++a)
        #pragma unroll
        for (int b2 = 0; b2 < 3; ++b2) {
            const int n = c * 9 + a * 3 + b2;
            const float v = xb[c * 16 + a * 4 + b2];
            acc_uc += v * w_uc[n * 32 + o];
            acc_pc += v * w_pc[o * 144 + n];
            acc_g  += v * w_wl[n];
        }
        const float g  = sigmoidf_(acc_g + b_wl[0]);
        hbuf[bl][o] = fmaxf((acc_uc + b_uc[o]) * g + (acc_pc + b_pc[o]) * (1.f - g), 0.f);
    }
    __syncthreads();

    if (threadIdx.x < 32) {
        const int bl2 = threadIdx.x >> 2;
        const int f   = threadIdx.x & 3;
        const int bb  = blockIdx.x * 8 + bl2;
        if (bb < B) {
            float s = fc_b[f];
            #pragma unroll
            for (int oo = 0; oo < 32; ++oo) s += hbuf[bl2][oo] * fc_w[oo * 4 + f];
            out[(size_t)bb * 4 + f] = s;
        }
    }
}

// ==========================================================================
extern "C" void kernel_launch(void* const* d_in, const int* in_sizes, int n_in,
                              void* d_out, int out_size, void* d_ws, size_t ws_size,
                              hipStream_t stream) {
    const float* x    = (const float*)d_in[0];
    const float* wuc1 = (const float*)d_in[1];
    const float* buc1 = (const float*)d_in[2];
    const float* wpc1 = (const float*)d_in[3];
    const float* bpc1 = (const float*)d_in[4];
    const float* wwl1 = (const float*)d_in[5];
    const float* bwl1 = (const float*)d_in[6];
    const float* wuc2 = (const float*)d_in[7];
    const float* buc2 = (const float*)d_in[8];
    const float* wpc2 = (const float*)d_in[9];
    const float* bpc2 = (const float*)d_in[10];
    const float* wwl2 = (const float*)d_in[11];
    const float* bwl2 = (const float*)d_in[12];
    const float* wuc3 = (const float*)d_in[13];
    const float* buc3 = (const float*)d_in[14];
    const float* wpc3 = (const float*)d_in[15];
    const float* bpc3 = (const float*)d_in[16];
    const float* wwl3 = (const float*)d_in[17];
    const float* bwl3 = (const float*)d_in[18];
    const float* wuc4 = (const float*)d_in[19];
    const float* buc4 = (const float*)d_in[20];
    const float* wpc4 = (const float*)d_in[21];
    const float* bpc4 = (const float*)d_in[22];
    const float* wwl4 = (const float*)d_in[23];
    const float* bwl4 = (const float*)d_in[24];
    const float* fcw  = (const float*)d_in[25];
    const float* fcb  = (const float*)d_in[26];

    const int B = in_sizes[0] / (3 * 64 * 64);   // 2048
    float* ws = (float*)d_ws;
    const size_t need = sizeof(float) * (size_t)(12288 + 1600 + 486 + 256) * B;

    if (ws_size >= need && (B % 256) == 0) {
        // ---------------- batch-last fast path ----------------
        float* xt = ws;                             // (12288, B)
        float* y1 = xt + (size_t)12288 * B;         // (1600, B)
        float* y2 = y1 + (size_t)1600 * B;          // (486, B)
        float* y3 = y2 + (size_t)486 * B;           // (256, B)

        transpose_kernel<<<dim3(12288 / 64, B / 64), 256, 0, stream>>>(x, xt, B, 12288);

        blockT_kernel<3, 4, 5, 3, 20, 64, 4>
            <<<dim3(B / 256, 100), 256, 0, stream>>>(xt, wuc1, buc1, wpc1, bpc1, wwl1, bwl1, y1, B);
        blockT_kernel<4, 6, 3, 2, 9, 20, 2>
            <<<dim3(B / 128, 21), 256, 0, stream>>>(y1, wuc2, buc2, wpc2, bpc2, wwl2, bwl2, y2, B);
        blockT_kernel<6, 16, 3, 2, 4, 9, 1>
            <<<dim3(B / 64, 4), 256, 0, stream>>>(y2, wuc3, buc3, wpc3, bpc3, wwl3, bwl3, y3, B);
        block4T_fc<<<B / 64, 256, 0, stream>>>(y3, wuc4, buc4, wpc4, bpc4, wwl4, bwl4,
                                               fcw, fcb, (float*)d_out, B);
    } else {
        // ---------------- fallback (round-1) ----------------
        float* y1 = ws;
        float* y2 = y1 + (size_t)B * 4 * 400;
        float* y3 = y2 + (size_t)B * 6 * 81;
        block_kernel<3, 4, 5, 3, 20, 64, 1>
            <<<B, 256, 0, stream>>>(x, wuc1, buc1, wpc1, bpc1, wwl1, bwl1, y1, B);
        block_kernel<4, 6, 3, 2, 9, 20, 4>
            <<<(B + 3) / 4, 256, 0, stream>>>(y1, wuc2, buc2, wpc2, bpc2, wwl2, bwl2, y2, B);
        block_kernel<6, 16, 3, 2, 4, 9, 16>
            <<<(B + 15) / 16, 256, 0, stream>>>(y2, wuc3, buc3, wpc3, bpc3, wwl3, bwl3, y3, B);
        block4_fc_kernel<<<(B + 7) / 8, 256, 0, stream>>>(
            y3, wuc4, buc4, wpc4, bpc4, wwl4, bwl4, fcw, fcb, (float*)d_out, B);
    }
}

// Round 3
// 114.050 us; speedup vs baseline: 1.7925x; 1.4464x over previous
//
#include <hip/hip_runtime.h>
#include <math.h>

// BlockNet: 4× (unfold-linear ⊕ conv ⊕ sigmoid-gate blend, ReLU) + FC(32->4).
// Strategy: transpose x to batch-last (P,B), then every block kernel uses
// lane=batch: weights wave-uniform, activations coalesced.
// Round 3: block4+FC rebuilt — weights staged in LDS (broadcast reads),
// per-channel register prefetch of activations for deep VMEM ILP.
// CFG: (cin,cout,k,s,oh) = (3,4,5,3,20),(4,6,3,2,9),(6,16,3,2,4),(16,32,3,2,1)

__device__ __forceinline__ float sigmoidf_(float x) {
    return 1.0f / (1.0f + expf(-x));
}

// ---------------- transpose: in (R,C) -> out (C,R), R=B, C=12288 ----------
__global__ __launch_bounds__(256)
void transpose_kernel(const float* __restrict__ in, float* __restrict__ out,
                      int R, int C)
{
    __shared__ float tile[64][65];
    const int c0 = blockIdx.x * 64;   // column block (pixel dim)
    const int r0 = blockIdx.y * 64;   // row block (batch dim)
    const int x  = threadIdx.x & 63;
    const int y0 = threadIdx.x >> 6;  // 0..3
    #pragma unroll
    for (int r = 0; r < 16; ++r) {
        const int row = y0 * 16 + r;                        // batch-local
        tile[x][row] = in[(size_t)(r0 + row) * C + c0 + x]; // coalesced read
    }
    __syncthreads();
    #pragma unroll
    for (int r = 0; r < 16; ++r) {
        const int prow = y0 * 16 + r;                       // pixel-local
        out[(size_t)(c0 + prow) * R + r0 + x] = tile[prow][x]; // coalesced write
    }
}

// ------------- batch-last block kernel: wave owns one location l ----------
// in_t (CIN*IH*IH, B) ; out_t (COUT*L, B).  VB batches per thread.
template<int CIN, int COUT, int K, int S, int OH, int IH, int VB>
__global__ __launch_bounds__(256)
void blockT_kernel(const float* __restrict__ in_t,
                   const float* __restrict__ w_uc,  // (L*LN, COUT)
                   const float* __restrict__ b_uc,  // (COUT*L)
                   const float* __restrict__ w_pc,  // (COUT, LN)
                   const float* __restrict__ b_pc,  // (COUT)
                   const float* __restrict__ w_wl,  // (LN)
                   const float* __restrict__ b_wl,  // (1)
                   float* __restrict__ out_t,
                   int B)
{
    constexpr int LN = CIN * K * K;
    constexpr int L  = OH * OH;
    const int wv   = threadIdx.x >> 6;
    const int lane = threadIdx.x & 63;
    const int l    = __builtin_amdgcn_readfirstlane(blockIdx.y * 4 + wv);
    if (l >= L) return;                       // wave-uniform, no syncthreads
    const int i = l / OH, j = l % OH;
    const int b = blockIdx.x * (64 * VB) + lane * VB;

    float au[COUT][VB], ap[COUT][VB], ag[VB];
    #pragma unroll
    for (int o = 0; o < COUT; ++o)
        #pragma unroll
        for (int q = 0; q < VB; ++q) { au[o][q] = 0.f; ap[o][q] = 0.f; }
    #pragma unroll
    for (int q = 0; q < VB; ++q) ag[q] = 0.f;

    const float* wu = w_uc + (size_t)l * LN * COUT;

    #pragma unroll
    for (int c = 0; c < CIN; ++c)
    #pragma unroll
    for (int a = 0; a < K; ++a)
    #pragma unroll
    for (int b2 = 0; b2 < K; ++b2) {
        const int n = c * K * K + a * K + b2;
        const int p = c * IH * IH + (i * S + a) * IH + (j * S + b2);
        float v[VB];
        const float* src = in_t + (size_t)p * B + b;
        if constexpr (VB == 4) {
            const float4 t = *reinterpret_cast<const float4*>(src);
            v[0] = t.x; v[1] = t.y; v[2] = t.z; v[3] = t.w;
        } else if constexpr (VB == 2) {
            const float2 t = *reinterpret_cast<const float2*>(src);
            v[0] = t.x; v[1] = t.y;
        } else {
            v[0] = src[0];
        }
        const float wl = w_wl[n];
        #pragma unroll
        for (int q = 0; q < VB; ++q) ag[q] += v[q] * wl;
        #pragma unroll
        for (int o = 0; o < COUT; ++o) {
            const float wuv = wu[n * COUT + o];     // scalar (l uniform)
            const float wpv = w_pc[o * LN + n];     // scalar
            #pragma unroll
            for (int q = 0; q < VB; ++q) {
                au[o][q] += v[q] * wuv;
                ap[o][q] += v[q] * wpv;
            }
        }
    }

    const float bwl = b_wl[0];
    float g[VB];
    #pragma unroll
    for (int q = 0; q < VB; ++q) g[q] = sigmoidf_(ag[q] + bwl);

    #pragma unroll
    for (int o = 0; o < COUT; ++o) {
        const float buc = b_uc[o * L + l];
        const float bpc = b_pc[o];
        float y[VB];
        #pragma unroll
        for (int q = 0; q < VB; ++q) {
            const float x1 = au[o][q] + buc;
            const float x2 = ap[o][q] + bpc;
            y[q] = fmaxf(x1 * g[q] + x2 * (1.f - g[q]), 0.f);
        }
        float* dst = out_t + (size_t)(o * L + l) * B + b;
        if constexpr (VB == 4) {
            float4 t; t.x = y[0]; t.y = y[1]; t.z = y[2]; t.w = y[3];
            *reinterpret_cast<float4*>(dst) = t;
        } else if constexpr (VB == 2) {
            float2 t; t.x = y[0]; t.y = y[1];
            *reinterpret_cast<float2*>(dst) = t;
        } else {
            dst[0] = y[0];
        }
    }
}

// ---------- block4 (cin=16,k=3,s=2,oh=1,cout=32) + FC(32->4), batch-last ---
// v2: all weights staged in LDS once per WG (coalesced), main loop reads
// broadcast float4s from LDS + register-prefetched activations (9/channel).
// grid = B/64, 256 threads: wave wv handles couts [8wv,8wv+8), lane=batch.
__global__ __launch_bounds__(256)
void block4T_fc(const float* __restrict__ in_t,  // (256, B)
                const float* __restrict__ w_uc,  // (144,32)
                const float* __restrict__ b_uc,  // (32)
                const float* __restrict__ w_pc,  // (32,144)
                const float* __restrict__ b_pc,  // (32)
                const float* __restrict__ w_wl,  // (144)
                const float* __restrict__ b_wl,  // (1)
                const float* __restrict__ fc_w,  // (32,4)
                const float* __restrict__ fc_b,  // (4)
                float* __restrict__ out,         // (B,4)
                int B)
{
    // stride 36 keeps 16B alignment for o0 in {0,8,16,24} and varies banks
    __shared__ __align__(16) float wu_s[144 * 36];
    __shared__ __align__(16) float wp_s[144 * 36];
    __shared__ float wl_s[144];
    __shared__ float buc_s[32], bpc_s[32], fcw_s[128], fcb_s[4];
    __shared__ float red[4][64][5];

    const int tid  = threadIdx.x;
    const int wv   = tid >> 6;
    const int lane = tid & 63;
    const int o0   = __builtin_amdgcn_readfirstlane(wv * 8);
    const int b    = blockIdx.x * 64 + lane;

    // ---- stage weights ----
    for (int idx = tid; idx < 144 * 32; idx += 256) {
        // w_uc already [n][o]: coalesced read, conflict-free LDS write
        wu_s[(idx >> 5) * 36 + (idx & 31)] = w_uc[idx];
        // w_pc is [o][n]: coalesced read, transposed LDS write
        const int o = idx / 144, n = idx - o * 144;
        wp_s[n * 36 + o] = w_pc[idx];
    }
    if (tid < 144) wl_s[tid] = w_wl[tid];
    if (tid < 32)  { buc_s[tid] = b_uc[tid]; bpc_s[tid] = b_pc[tid]; }
    if (tid >= 64 && tid < 192) fcw_s[tid - 64] = fc_w[tid - 64];
    if (tid >= 192 && tid < 196) fcb_s[tid - 192] = fc_b[tid - 192];
    __syncthreads();

    float au[8], apc[8], ag = 0.f;
    #pragma unroll
    for (int oo = 0; oo < 8; ++oo) { au[oo] = 0.f; apc[oo] = 0.f; }

    #pragma unroll
    for (int c = 0; c < 16; ++c) {
        // prefetch the 9 used taps of this channel (independent loads)
        float v[9];
        #pragma unroll
        for (int a = 0; a < 3; ++a)
        #pragma unroll
        for (int b2 = 0; b2 < 3; ++b2)
            v[a * 3 + b2] = in_t[(size_t)(c * 16 + a * 4 + b2) * B + b];

        #pragma unroll
        for (int t = 0; t < 9; ++t) {
            const int n = c * 9 + t;
            ag += v[t] * wl_s[n];
            const float4 wuA = *reinterpret_cast<const float4*>(&wu_s[n * 36 + o0]);
            const float4 wuB = *reinterpret_cast<const float4*>(&wu_s[n * 36 + o0 + 4]);
            const float4 wpA = *reinterpret_cast<const float4*>(&wp_s[n * 36 + o0]);
            const float4 wpB = *reinterpret_cast<const float4*>(&wp_s[n * 36 + o0 + 4]);
            au[0] += v[t] * wuA.x;  au[1] += v[t] * wuA.y;
            au[2] += v[t] * wuA.z;  au[3] += v[t] * wuA.w;
            au[4] += v[t] * wuB.x;  au[5] += v[t] * wuB.y;
            au[6] += v[t] * wuB.z;  au[7] += v[t] * wuB.w;
            apc[0] += v[t] * wpA.x; apc[1] += v[t] * wpA.y;
            apc[2] += v[t] * wpA.z; apc[3] += v[t] * wpA.w;
            apc[4] += v[t] * wpB.x; apc[5] += v[t] * wpB.y;
            apc[6] += v[t] * wpB.z; apc[7] += v[t] * wpB.w;
        }
    }

    const float g = sigmoidf_(ag + b_wl[0]);
    float pf[4] = {0.f, 0.f, 0.f, 0.f};
    #pragma unroll
    for (int oo = 0; oo < 8; ++oo) {
        const int o = o0 + oo;
        const float h = fmaxf((au[oo] + buc_s[o]) * g +
                              (apc[oo] + bpc_s[o]) * (1.f - g), 0.f);
        #pragma unroll
        for (int f = 0; f < 4; ++f) pf[f] += h * fcw_s[o * 4 + f];
    }
    #pragma unroll
    for (int f = 0; f < 4; ++f) red[wv][lane][f] = pf[f];
    __syncthreads();
    if (wv == 0) {
        float4 s;
        s.x = fcb_s[0] + red[0][lane][0] + red[1][lane][0] + red[2][lane][0] + red[3][lane][0];
        s.y = fcb_s[1] + red[0][lane][1] + red[1][lane][1] + red[2][lane][1] + red[3][lane][1];
        s.z = fcb_s[2] + red[0][lane][2] + red[1][lane][2] + red[2][lane][2] + red[3][lane][2];
        s.w = fcb_s[3] + red[0][lane][3] + red[1][lane][3] + red[2][lane][3] + red[3][lane][3];
        *reinterpret_cast<float4*>(out + (size_t)b * 4) = s;
    }
}

// ======================= fallback path (round-1, NCHW) ====================
template<int CIN, int COUT, int K, int S, int OH, int IH, int BPB>
__global__ __launch_bounds__(256)
void block_kernel(const float* __restrict__ in,
                  const float* __restrict__ w_uc,
                  const float* __restrict__ b_uc,
                  const float* __restrict__ w_pc,
                  const float* __restrict__ b_pc,
                  const float* __restrict__ w_wl,
                  const float* __restrict__ b_wl,
                  float* __restrict__ out,
                  int B)
{
    constexpr int LN   = CIN * K * K;
    constexpr int L    = OH * OH;
    constexpr int TILE = CIN * IH * IH;
    __shared__ __align__(16) float lds[BPB * TILE];

    const int b0 = blockIdx.x * BPB;
    const int nb = (B - b0 < BPB) ? (B - b0) : BPB;
    const int tot = nb * TILE;
    const float* src = in + (size_t)b0 * TILE;
    if ((tot & 3) == 0) {
        const float4* s4 = reinterpret_cast<const float4*>(src);
        float4* d4 = reinterpret_cast<float4*>(lds);
        for (int idx = threadIdx.x; idx < (tot >> 2); idx += blockDim.x) d4[idx] = s4[idx];
    } else {
        for (int idx = threadIdx.x; idx < tot; idx += blockDim.x) lds[idx] = src[idx];
    }
    __syncthreads();

    const float bwl = b_wl[0];
    for (int t = threadIdx.x; t < nb * L; t += blockDim.x) {
        const int bb = t / L;
        const int l  = t % L;
        const int i  = l / OH, j = l % OH;
        const float* tile = lds + bb * TILE;

        float acc_uc[COUT], acc_pc[COUT];
        #pragma unroll
        for (int o = 0; o < COUT; ++o) { acc_uc[o] = 0.f; acc_pc[o] = 0.f; }
        float acc_g = 0.f;

        const float* wu = w_uc + (size_t)l * LN * COUT;
        #pragma unroll
        for (int c = 0; c < CIN; ++c)
        #pragma unroll
        for (int a = 0; a < K; ++a)
        #pragma unroll
        for (int b2 = 0; b2 < K; ++b2) {
            const int n = c * K * K + a * K + b2;
            const float v = tile[c * IH * IH + (i * S + a) * IH + (j * S + b2)];
            acc_g += v * w_wl[n];
            #pragma unroll
            for (int o = 0; o < COUT; ++o) acc_uc[o] += v * wu[n * COUT + o];
            #pragma unroll
            for (int o = 0; o < COUT; ++o) acc_pc[o] += v * w_pc[o * LN + n];
        }

        const float g = sigmoidf_(acc_g + bwl);
        const size_t ob = (size_t)(b0 + bb) * COUT * L;
        #pragma unroll
        for (int o = 0; o < COUT; ++o) {
            const float x1 = acc_uc[o] + b_uc[o * L + l];
            const float x2 = acc_pc[o] + b_pc[o];
            out[ob + o * L + l] = fmaxf(x1 * g + x2 * (1.f - g), 0.f);
        }
    }
}

__global__ __launch_bounds__(256)
void block4_fc_kernel(const float* __restrict__ in,
                      const float* __restrict__ w_uc,
                      const float* __restrict__ b_uc,
                      const float* __restrict__ w_pc,
                      const float* __restrict__ b_pc,
                      const float* __restrict__ w_wl,
                      const float* __restrict__ b_wl,
                      const float* __restrict__ fc_w,
                      const float* __restrict__ fc_b,
                      float* __restrict__ out,
                      int B)
{
    __shared__ float hbuf[8][32];
    const int bl = threadIdx.x >> 5;
    const int o  = threadIdx.x & 31;
    const int b  = blockIdx.x * 8 + bl;

    if (b < B) {
        const float* xb = in + (size_t)b * 256;
        float acc_uc = 0.f, acc_pc = 0.f, acc_g = 0.f;
        #pragma unroll
        for (int c = 0; c < 16; ++c)
        #pragma unroll
        for (int a = 0; a < 3; ++a)
        #pragma unroll
        for (int b2 = 0; b2 < 3; ++b2) {
            const int n = c * 9 + a * 3 + b2;
            const float v = xb[c * 16 + a * 4 + b2];
            acc_uc += v * w_uc[n * 32 + o];
            acc_pc += v * w_pc[o * 144 + n];
            acc_g  += v * w_wl[n];
        }
        const float g  = sigmoidf_(acc_g + b_wl[0]);
        hbuf[bl][o] = fmaxf((acc_uc + b_uc[o]) * g + (acc_pc + b_pc[o]) * (1.f - g), 0.f);
    }
    __syncthreads();

    if (threadIdx.x < 32) {
        const int bl2 = threadIdx.x >> 2;
        const int f   = threadIdx.x & 3;
        const int bb  = blockIdx.x * 8 + bl2;
        if (bb < B) {
            float s = fc_b[f];
            #pragma unroll
            for (int oo = 0; oo < 32; ++oo) s += hbuf[bl2][oo] * fc_w[oo * 4 + f];
            out[(size_t)bb * 4 + f] = s;
        }
    }
}

// ==========================================================================
extern "C" void kernel_launch(void* const* d_in, const int* in_sizes, int n_in,
                              void* d_out, int out_size, void* d_ws, size_t ws_size,
                              hipStream_t stream) {
    const float* x    = (const float*)d_in[0];
    const float* wuc1 = (const float*)d_in[1];
    const float* buc1 = (const float*)d_in[2];
    const float* wpc1 = (const float*)d_in[3];
    const float* bpc1 = (const float*)d_in[4];
    const float* wwl1 = (const float*)d_in[5];
    const float* bwl1 = (const float*)d_in[6];
    const float* wuc2 = (const float*)d_in[7];
    const float* buc2 = (const float*)d_in[8];
    const float* wpc2 = (const float*)d_in[9];
    const float* bpc2 = (const float*)d_in[10];
    const float* wwl2 = (const float*)d_in[11];
    const float* bwl2 = (const float*)d_in[12];
    const float* wuc3 = (const float*)d_in[13];
    const float* buc3 = (const float*)d_in[14];
    const float* wpc3 = (const float*)d_in[15];
    const float* bpc3 = (const float*)d_in[16];
    const float* wwl3 = (const float*)d_in[17];
    const float* bwl3 = (const float*)d_in[18];
    const float* wuc4 = (const float*)d_in[19];
    const float* buc4 = (const float*)d_in[20];
    const float* wpc4 = (const float*)d_in[21];
    const float* bpc4 = (const float*)d_in[22];
    const float* wwl4 = (const float*)d_in[23];
    const float* bwl4 = (const float*)d_in[24];
    const float* fcw  = (const float*)d_in[25];
    const float* fcb  = (const float*)d_in[26];

    const int B = in_sizes[0] / (3 * 64 * 64);   // 2048
    float* ws = (float*)d_ws;
    const size_t need = sizeof(float) * (size_t)(12288 + 1600 + 486 + 256) * B;

    if (ws_size >= need && (B % 256) == 0) {
        // ---------------- batch-last fast path ----------------
        float* xt = ws;                             // (12288, B)
        float* y1 = xt + (size_t)12288 * B;         // (1600, B)
        float* y2 = y1 + (size_t)1600 * B;          // (486, B)
        float* y3 = y2 + (size_t)486 * B;           // (256, B)

        transpose_kernel<<<dim3(12288 / 64, B / 64), 256, 0, stream>>>(x, xt, B, 12288);

        blockT_kernel<3, 4, 5, 3, 20, 64, 4>
            <<<dim3(B / 256, 100), 256, 0, stream>>>(xt, wuc1, buc1, wpc1, bpc1, wwl1, bwl1, y1, B);
        blockT_kernel<4, 6, 3, 2, 9, 20, 2>
            <<<dim3(B / 128, 21), 256, 0, stream>>>(y1, wuc2, buc2, wpc2, bpc2, wwl2, bwl2, y2, B);
        blockT_kernel<6, 16, 3, 2, 4, 9, 1>
            <<<dim3(B / 64, 4), 256, 0, stream>>>(y2, wuc3, buc3, wpc3, bpc3, wwl3, bwl3, y3, B);
        block4T_fc<<<B / 64, 256, 0, stream>>>(y3, wuc4, buc4, wpc4, bpc4, wwl4, bwl4,
                                               fcw, fcb, (float*)d_out, B);
    } else {
        // ---------------- fallback (round-1) ----------------
        float* y1 = ws;
        float* y2 = y1 + (size_t)B * 4 * 400;
        float* y3 = y2 + (size_t)B * 6 * 81;
        block_kernel<3, 4, 5, 3, 20, 64, 1>
            <<<B, 256, 0, stream>>>(x, wuc1, buc1, wpc1, bpc1, wwl1, bwl1, y1, B);
        block_kernel<4, 6, 3, 2, 9, 20, 4>
            <<<(B + 3) / 4, 256, 0, stream>>>(y1, wuc2, buc2, wpc2, bpc2, wwl2, bwl2, y2, B);
        block_kernel<6, 16, 3, 2, 4, 9, 16>
            <<<(B + 15) / 16, 256, 0, stream>>>(y2, wuc3, buc3, wpc3, bpc3, wwl3, bwl3, y3, B);
        block4_fc_kernel<<<(B + 7) / 8, 256, 0, stream>>>(
            y3, wuc4, buc4, wpc4, bpc4, wwl4, bwl4, fcw, fcb, (float*)d_out, B);
    }
}